// Round 1
// baseline (3773.430 us; speedup 1.0000x reference)
//
#include <hip/hip_runtime.h>
#include <math.h>

#define NN 100000   // nodes
#define NE 400000   // edges
#define NG 2000     // graphs
#define F0 84       // num_features_xd
#define F2 840      // F0*10
#define FH 1024     // fc hidden
#define FO 384      // fc out
#define FXG 1680    // 2*F2

// scatter-add over edges: agg[dst[e]] += x[src[e]], feature dim F0, float4-chunked
__global__ void scatter_add_f84(const float* __restrict__ x,
                                const int* __restrict__ src,
                                const int* __restrict__ dst,
                                float* __restrict__ agg) {
    const int per_edge = F0 / 4;  // 21
    int idx = blockIdx.x * blockDim.x + threadIdx.x;
    if (idx >= NE * per_edge) return;
    int e  = idx / per_edge;
    int f4 = (idx - e * per_edge) * 4;
    int s = src[e], d = dst[e];
    const float4 v = *reinterpret_cast<const float4*>(x + (size_t)s * F0 + f4);
    float* base = agg + (size_t)d * F0 + f4;
    atomicAdd(base + 0, v.x);
    atomicAdd(base + 1, v.y);
    atomicAdd(base + 2, v.z);
    atomicAdd(base + 3, v.w);
}

// out[row, c4..c4+3] = relu(b + sum_k (h[row,k]+agg[row,k]) * W[k, c4..c4+3])
__global__ void gin_dense(const float* __restrict__ h,
                          const float* __restrict__ agg,
                          const float* __restrict__ W,
                          const float* __restrict__ b,
                          float* __restrict__ out,
                          int n, int fin, int fout) {
    int q = fout >> 2;
    int idx = blockIdx.x * blockDim.x + threadIdx.x;
    if (idx >= n * q) return;
    int row = idx / q;
    int c4  = (idx - row * q) << 2;
    const float* hr = h   + (size_t)row * fin;
    const float* ar = agg + (size_t)row * fin;
    float a0 = b[c4], a1 = b[c4 + 1], a2 = b[c4 + 2], a3 = b[c4 + 3];
    for (int k = 0; k < fin; ++k) {
        float s = hr[k] + ar[k];
        const float4 w = *reinterpret_cast<const float4*>(W + (size_t)k * fout + c4);
        a0 += s * w.x; a1 += s * w.y; a2 += s * w.z; a3 += s * w.w;
    }
    float* o = out + (size_t)row * fout + c4;
    o[0] = fmaxf(a0, 0.f);
    o[1] = fmaxf(a1, 0.f);
    o[2] = fmaxf(a2, 0.f);
    o[3] = fmaxf(a3, 0.f);
}

// plain dense: out = in @ W + b, optional relu
template <bool RELU>
__global__ void fc_dense(const float* __restrict__ in,
                         const float* __restrict__ W,
                         const float* __restrict__ b,
                         float* __restrict__ out,
                         int n, int fin, int fout) {
    int q = fout >> 2;
    int idx = blockIdx.x * blockDim.x + threadIdx.x;
    if (idx >= n * q) return;
    int row = idx / q;
    int c4  = (idx - row * q) << 2;
    const float* ir = in + (size_t)row * fin;
    float a0 = b[c4], a1 = b[c4 + 1], a2 = b[c4 + 2], a3 = b[c4 + 3];
    for (int k = 0; k < fin; ++k) {
        float s = ir[k];
        const float4 w = *reinterpret_cast<const float4*>(W + (size_t)k * fout + c4);
        a0 += s * w.x; a1 += s * w.y; a2 += s * w.z; a3 += s * w.w;
    }
    float* o = out + (size_t)row * fout + c4;
    if (RELU) {
        o[0] = fmaxf(a0, 0.f); o[1] = fmaxf(a1, 0.f);
        o[2] = fmaxf(a2, 0.f); o[3] = fmaxf(a3, 0.f);
    } else {
        o[0] = a0; o[1] = a1; o[2] = a2; o[3] = a3;
    }
}

// gstart[g] = first node index with batch >= g; gstart[NG] = NN (batch sorted)
__global__ void graph_starts(const int* __restrict__ batch, int* __restrict__ gstart) {
    int i = blockIdx.x * blockDim.x + threadIdx.x;
    if (i >= NN) return;
    int b = batch[i];
    if (i == 0) {
        for (int g = 0; g <= b; ++g) gstart[g] = 0;
    } else {
        int bp = batch[i - 1];
        for (int g = bp + 1; g <= b; ++g) gstart[g] = i;
    }
    if (i == NN - 1) {
        for (int g = b + 1; g <= NG; ++g) gstart[g] = NN;
    }
}

// block per graph: pool_max -> xg[g, 0:840], pool_sum -> xg[g, 840:1680]
__global__ void pool_kernel(const float* __restrict__ h2,
                            const int* __restrict__ gstart,
                            float* __restrict__ xg) {
    int g = blockIdx.x;
    int t = threadIdx.x;  // 256 threads
    int s = gstart[g], e = gstart[g + 1];
    float sm[4] = {0.f, 0.f, 0.f, 0.f};
    float mx[4] = {-INFINITY, -INFINITY, -INFINITY, -INFINITY};
    for (int n = s; n < e; ++n) {
        const float* row = h2 + (size_t)n * F2;
#pragma unroll
        for (int u = 0; u < 4; ++u) {
            int f = t + u * 256;
            if (f < F2) {
                float v = row[f];
                sm[u] += v;
                mx[u] = fmaxf(mx[u], v);
            }
        }
    }
    float* xr = xg + (size_t)g * FXG;
#pragma unroll
    for (int u = 0; u < 4; ++u) {
        int f = t + u * 256;
        if (f < F2) {
            xr[f]      = mx[u];
            xr[F2 + f] = sm[u];
        }
    }
}

extern "C" void kernel_launch(void* const* d_in, const int* in_sizes, int n_in,
                              void* d_out, int out_size, void* d_ws, size_t ws_size,
                              hipStream_t stream) {
    const float* x    = (const float*)d_in[0];
    const int*   ei   = (const int*)d_in[1];
    const int*   batch= (const int*)d_in[2];
    const float* W1   = (const float*)d_in[3];
    const float* b1   = (const float*)d_in[4];
    const float* W2   = (const float*)d_in[5];
    const float* b2   = (const float*)d_in[6];
    const float* Wf1  = (const float*)d_in[7];
    const float* bf1  = (const float*)d_in[8];
    const float* Wf2  = (const float*)d_in[9];
    const float* bf2  = (const float*)d_in[10];

    const int* src = ei;       // edge_index[0]
    const int* dst = ei + NE;  // edge_index[1]

    float* xg_out = (float*)d_out;                    // [NG, FO]
    float* h2     = (float*)d_out + (size_t)NG * FO;  // [NN, F2]

    float* agg  = (float*)d_ws;                       // [NN, F0]
    float* h1   = agg + (size_t)NN * F0;              // [NN, F0]
    float* xg   = h1  + (size_t)NN * F0;              // [NG, FXG]
    float* fc1  = xg  + (size_t)NG * FXG;             // [NG, FH]
    int*   gst  = (int*)(fc1 + (size_t)NG * FH);      // [NG+1]

    const int blk = 256;

    // ---- conv1: agg = scatter_add(x); h1 = relu((x+agg)@W1 + b1)
    hipMemsetAsync(agg, 0, (size_t)NN * F0 * sizeof(float), stream);
    {
        int total = NE * (F0 / 4);
        scatter_add_f84<<<(total + blk - 1) / blk, blk, 0, stream>>>(x, src, dst, agg);
    }
    {
        int total = NN * (F0 / 4);
        gin_dense<<<(total + blk - 1) / blk, blk, 0, stream>>>(x, agg, W1, b1, h1, NN, F0, F0);
    }

    // ---- conv2: agg = scatter_add(h1); h2 = relu((h1+agg)@W2 + b2)
    hipMemsetAsync(agg, 0, (size_t)NN * F0 * sizeof(float), stream);
    {
        int total = NE * (F0 / 4);
        scatter_add_f84<<<(total + blk - 1) / blk, blk, 0, stream>>>(h1, src, dst, agg);
    }
    {
        int total = NN * (F2 / 4);
        gin_dense<<<(total + blk - 1) / blk, blk, 0, stream>>>(h1, agg, W2, b2, h2, NN, F0, F2);
    }

    // ---- pooling
    graph_starts<<<(NN + blk - 1) / blk, blk, 0, stream>>>(batch, gst);
    pool_kernel<<<NG, blk, 0, stream>>>(h2, gst, xg);

    // ---- fc head
    {
        int total = NG * (FH / 4);
        fc_dense<true><<<(total + blk - 1) / blk, blk, 0, stream>>>(xg, Wf1, bf1, fc1, NG, FXG, FH);
    }
    {
        int total = NG * (FO / 4);
        fc_dense<false><<<(total + blk - 1) / blk, blk, 0, stream>>>(fc1, Wf2, bf2, xg_out, NG, FH, FO);
    }
}

// Round 2
// 1501.274 us; speedup vs baseline: 2.5135x; 2.5135x over previous
//
#include <hip/hip_runtime.h>
#include <math.h>

#define NN 100000   // nodes
#define NE 400000   // edges
#define NG 2000     // graphs
#define F0 84       // num_features_xd
#define F2 840      // F0*10
#define FH 1024     // fc hidden
#define FO 384      // fc out

typedef __attribute__((ext_vector_type(8))) short bf16x8;
typedef __attribute__((ext_vector_type(4))) float f32x4;

// round-to-nearest-even float -> bf16 (as short)
__device__ inline short f2bf(float f) {
    union { float f; unsigned u; } v; v.f = f;
    unsigned r = (v.u + 0x7FFFu + ((v.u >> 16) & 1u)) >> 16;
    return (short)r;
}

// ---------------- scatter-add over edges (fp32 atomics) ----------------
__global__ void scatter_add_f84(const float* __restrict__ x,
                                const int* __restrict__ src,
                                const int* __restrict__ dst,
                                float* __restrict__ agg) {
    const int per_edge = F0 / 4;  // 21
    int idx = blockIdx.x * blockDim.x + threadIdx.x;
    if (idx >= NE * per_edge) return;
    int e  = idx / per_edge;
    int f4 = (idx - e * per_edge) * 4;
    int s = src[e], d = dst[e];
    const float4 v = *reinterpret_cast<const float4*>(x + (size_t)s * F0 + f4);
    float* base = agg + (size_t)d * F0 + f4;
    atomicAdd(base + 0, v.x);
    atomicAdd(base + 1, v.y);
    atomicAdd(base + 2, v.z);
    atomicAdd(base + 3, v.w);
}

// ---------------- prep: A = bf16(h + agg), padded [NN][96] ----------------
__global__ void prep_a(const float* __restrict__ h, const float* __restrict__ agg,
                       short* __restrict__ A) {
    int idx = blockIdx.x * blockDim.x + threadIdx.x;  // NN*12 chunks of 8
    if (idx >= NN * 12) return;
    int row = idx / 12;
    int k0  = (idx - row * 12) * 8;
    bf16x8 v;
#pragma unroll
    for (int j = 0; j < 8; ++j) {
        int k = k0 + j;
        float s = (k < F0) ? h[(size_t)row * F0 + k] + agg[(size_t)row * F0 + k] : 0.f;
        v[j] = f2bf(s);
    }
    *reinterpret_cast<bf16x8*>(A + (size_t)row * 96 + k0) = v;
}

// ---------------- pack W [K][N] fp32 -> fragment-ordered bf16 ----------------
// P[((ct*KB + kb)*64 + lane)*8 + j] = W[kb*32 + (lane>>4)*8 + j][ct*16 + (lane&15)]
__global__ void pack_w(const float* __restrict__ W, short* __restrict__ P,
                       int K, int N, int KB, int CT) {
    int idx = blockIdx.x * blockDim.x + threadIdx.x;
    if (idx >= CT * KB * 64) return;
    int lane = idx & 63;
    int t    = idx >> 6;
    int kb   = t % KB;
    int ct   = t / KB;
    int col  = ct * 16 + (lane & 15);
    int k0   = kb * 32 + ((lane >> 4) << 3);
    bf16x8 v;
#pragma unroll
    for (int j = 0; j < 8; ++j) {
        int k = k0 + j;
        float f = (k < K && col < N) ? W[(size_t)k * N + col] : 0.f;
        v[j] = f2bf(f);
    }
    *reinterpret_cast<bf16x8*>(P + (size_t)idx * 8) = v;
}

// ---------------- MFMA GEMM: C[M x N] = act(A_bf16[M x Kp] @ Bpack + bias) ----
// one wave = 16 rows x 32 cols (2 col-tiles); grid covers rowTiles*ctPairs waves
template <bool RELU, bool OUTBF16>
__global__ void gemm16(const short* __restrict__ A, const short* __restrict__ Bp,
                       const float* __restrict__ bias, void* __restrict__ Cout,
                       int Kp, int N, int rowTiles, int ctPairs) {
    int gid  = blockIdx.x * blockDim.x + threadIdx.x;
    int w    = gid >> 6;
    if (w >= rowTiles * ctPairs) return;
    int lane = gid & 63;
    int rt   = w / ctPairs;
    int cp   = w - rt * ctPairs;
    int KB   = Kp >> 5;
    const short* Ap = A + (size_t)(rt * 16 + (lane & 15)) * Kp + ((lane >> 4) << 3);
    const short* B0 = Bp + (size_t)(cp * 2) * KB * 512 + lane * 8;
    const short* B1 = B0 + (size_t)KB * 512;
    f32x4 c0 = {0.f, 0.f, 0.f, 0.f}, c1 = {0.f, 0.f, 0.f, 0.f};
    for (int kb = 0; kb < KB; ++kb) {
        bf16x8 a  = *reinterpret_cast<const bf16x8*>(Ap + kb * 32);
        bf16x8 b0 = *reinterpret_cast<const bf16x8*>(B0 + kb * 512);
        bf16x8 b1 = *reinterpret_cast<const bf16x8*>(B1 + kb * 512);
        c0 = __builtin_amdgcn_mfma_f32_16x16x32_bf16(a, b0, c0, 0, 0, 0);
        c1 = __builtin_amdgcn_mfma_f32_16x16x32_bf16(a, b1, c1, 0, 0, 0);
    }
    int col0 = cp * 32 + (lane & 15);
    int col1 = col0 + 16;
    int row0 = rt * 16 + ((lane >> 4) << 2);
    float bias0 = (col0 < N) ? bias[col0] : 0.f;
    float bias1 = (col1 < N) ? bias[col1] : 0.f;
#pragma unroll
    for (int r = 0; r < 4; ++r) {
        int row = row0 + r;
        float v0 = c0[r] + bias0, v1 = c1[r] + bias1;
        if (RELU) { v0 = fmaxf(v0, 0.f); v1 = fmaxf(v1, 0.f); }
        if (OUTBF16) {
            short* C = (short*)Cout;
            if (col0 < N) C[(size_t)row * N + col0] = f2bf(v0);
            if (col1 < N) C[(size_t)row * N + col1] = f2bf(v1);
        } else {
            float* C = (float*)Cout;
            if (col0 < N) C[(size_t)row * N + col0] = v0;
            if (col1 < N) C[(size_t)row * N + col1] = v1;
        }
    }
}

// ---------------- graph starts (batch sorted) ----------------
__global__ void graph_starts(const int* __restrict__ batch, int* __restrict__ gstart) {
    int i = blockIdx.x * blockDim.x + threadIdx.x;
    if (i >= NN) return;
    int b = batch[i];
    if (i == 0) {
        for (int g = 0; g <= b; ++g) gstart[g] = 0;
    } else {
        int bp = batch[i - 1];
        for (int g = bp + 1; g <= b; ++g) gstart[g] = i;
    }
    if (i == NN - 1) {
        for (int g = b + 1; g <= NG; ++g) gstart[g] = NN;
    }
}

// ---------------- pool: writes bf16 [NG][1696]: [max(840) | sum(840) | 0 pad] --
__global__ void pool_kernel(const float* __restrict__ h2,
                            const int* __restrict__ gstart,
                            short* __restrict__ A3) {
    int g = blockIdx.x;
    int t = threadIdx.x;  // 256
    int s = gstart[g], e = gstart[g + 1];
    float sm[4] = {0.f, 0.f, 0.f, 0.f};
    float mx[4] = {-INFINITY, -INFINITY, -INFINITY, -INFINITY};
    for (int n = s; n < e; ++n) {
        const float* row = h2 + (size_t)n * F2;
#pragma unroll
        for (int u = 0; u < 4; ++u) {
            int f = t + u * 256;
            if (f < F2) {
                float v = row[f];
                sm[u] += v;
                mx[u] = fmaxf(mx[u], v);
            }
        }
    }
    short* xr = A3 + (size_t)g * 1696;
#pragma unroll
    for (int u = 0; u < 4; ++u) {
        int f = t + u * 256;
        if (f < F2) {
            xr[f]      = f2bf(mx[u]);
            xr[F2 + f] = f2bf(sm[u]);
        }
    }
    if (t < 16) xr[1680 + t] = 0;
}

extern "C" void kernel_launch(void* const* d_in, const int* in_sizes, int n_in,
                              void* d_out, int out_size, void* d_ws, size_t ws_size,
                              hipStream_t stream) {
    const float* x    = (const float*)d_in[0];
    const int*   ei   = (const int*)d_in[1];
    const int*   batch= (const int*)d_in[2];
    const float* W1   = (const float*)d_in[3];
    const float* b1   = (const float*)d_in[4];
    const float* W2   = (const float*)d_in[5];
    const float* b2   = (const float*)d_in[6];
    const float* Wf1  = (const float*)d_in[7];
    const float* bf1  = (const float*)d_in[8];
    const float* Wf2  = (const float*)d_in[9];
    const float* bf2  = (const float*)d_in[10];

    const int* src = ei;
    const int* dst = ei + NE;

    float* xg_out = (float*)d_out;                    // [NG, FO]
    float* h2     = (float*)d_out + (size_t)NG * FO;  // [NN, F2]

    // workspace layout
    float* agg  = (float*)d_ws;                        // NN*84 f32
    float* h1   = agg + (size_t)NN * F0;               // NN*84 f32
    short* Abuf = (short*)(h1 + (size_t)NN * F0);      // NN*96 bf16 (reused)
    short* A3   = Abuf;                                // [NG][1696] bf16 (pool out)
    short* fc1o = Abuf + (size_t)NG * 1696;            // [NG][1024] bf16
    short* W1p  = Abuf + (size_t)NN * 96;              // 6*3*512
    short* W2p  = W1p + 6 * 3 * 512;                   // 54*3*512
    short* Wf1p = W2p + 54 * 3 * 512;                  // 64*53*512
    short* Wf2p = Wf1p + (size_t)64 * 53 * 512;        // 24*32*512
    int*   gst  = (int*)(Wf2p + (size_t)24 * 32 * 512);// NG+1

    const int blk = 256;
    auto cdiv = [](long long a, long long b) { return (int)((a + b - 1) / b); };

    // ---- pack weights (every call; tiny) ----
    pack_w<<<cdiv(6 * 3 * 64, blk), blk, 0, stream>>>(W1, W1p, F0, F0, 3, 6);
    pack_w<<<cdiv(54 * 3 * 64, blk), blk, 0, stream>>>(W2, W2p, F0, F2, 3, 54);
    pack_w<<<cdiv(64 * 53 * 64, blk), blk, 0, stream>>>(Wf1, Wf1p, 1680, FH, 53, 64);
    pack_w<<<cdiv(24 * 32 * 64, blk), blk, 0, stream>>>(Wf2, Wf2p, FH, FO, 32, 24);

    // ---- conv1 ----
    hipMemsetAsync(agg, 0, (size_t)NN * F0 * sizeof(float), stream);
    scatter_add_f84<<<cdiv((long long)NE * 21, blk), blk, 0, stream>>>(x, src, dst, agg);
    prep_a<<<cdiv((long long)NN * 12, blk), blk, 0, stream>>>(x, agg, Abuf);
    {
        long long waves = 6250LL * 3;
        gemm16<true, false><<<cdiv(waves * 64, blk), blk, 0, stream>>>(
            Abuf, W1p, b1, h1, 96, F0, 6250, 3);
    }

    // ---- conv2 ----
    hipMemsetAsync(agg, 0, (size_t)NN * F0 * sizeof(float), stream);
    scatter_add_f84<<<cdiv((long long)NE * 21, blk), blk, 0, stream>>>(h1, src, dst, agg);
    prep_a<<<cdiv((long long)NN * 12, blk), blk, 0, stream>>>(h1, agg, Abuf);
    {
        long long waves = 6250LL * 27;
        gemm16<true, false><<<cdiv(waves * 64, blk), blk, 0, stream>>>(
            Abuf, W2p, b2, h2, 96, F2, 6250, 27);
    }

    // ---- pooling ----
    graph_starts<<<cdiv(NN, blk), blk, 0, stream>>>(batch, gst);
    pool_kernel<<<NG, blk, 0, stream>>>(h2, gst, A3);

    // ---- fc head ----
    {
        long long waves = 125LL * 32;
        gemm16<true, true><<<cdiv(waves * 64, blk), blk, 0, stream>>>(
            A3, Wf1p, bf1, fc1o, 1696, FH, 125, 32);
    }
    {
        long long waves = 125LL * 12;
        gemm16<false, false><<<cdiv(waves * 64, blk), blk, 0, stream>>>(
            fc1o, Wf2p, bf2, xg_out, 1024, FO, 125, 12);
    }
}

// Round 3
// 663.560 us; speedup vs baseline: 5.6866x; 2.2625x over previous
//
#include <hip/hip_runtime.h>
#include <math.h>

#define NN 100000   // nodes
#define NE 400000   // edges
#define NG 2000     // graphs
#define F0 84       // num_features_xd
#define F2 840      // F0*10
#define FH 1024     // fc hidden
#define FO 384      // fc out

typedef __attribute__((ext_vector_type(8))) short bf16x8;
typedef __attribute__((ext_vector_type(4))) float f32x4;

// round-to-nearest-even float -> bf16 (as short)
__device__ inline short f2bf(float f) {
    union { float f; unsigned u; } v; v.f = f;
    unsigned r = (v.u + 0x7FFFu + ((v.u >> 16) & 1u)) >> 16;
    return (short)r;
}

// ---------------- CSR build ----------------
__global__ void edge_deg(const int* __restrict__ dst, int* __restrict__ deg) {
    int e = blockIdx.x * blockDim.x + threadIdx.x;
    if (e < NE) atomicAdd(&deg[dst[e]], 1);
}

// single-block exclusive scan of deg[NN] -> rowptr[NN+1]
__global__ void scan_deg(const int* __restrict__ deg, int* __restrict__ rowptr) {
    const int T = 1024;
    const int CH = (NN + T - 1) / T;  // 98
    int t = threadIdx.x;
    int lo = t * CH, hi = min(lo + CH, NN);
    int s = 0;
    for (int i = lo; i < hi; ++i) s += deg[i];
    __shared__ int sums[T];
    sums[t] = s;
    __syncthreads();
    for (int d = 1; d < T; d <<= 1) {
        int v = (t >= d) ? sums[t - d] : 0;
        __syncthreads();
        sums[t] += v;
        __syncthreads();
    }
    int off = (t == 0) ? 0 : sums[t - 1];
    for (int i = lo; i < hi; ++i) { rowptr[i] = off; off += deg[i]; }
    if (t == T - 1) rowptr[NN] = off;  // thread 1023 has empty chunk; off == total
}

__global__ void edge_fill(const int* __restrict__ src, const int* __restrict__ dst,
                          const int* __restrict__ rowptr, int* __restrict__ cnt,
                          int* __restrict__ eid) {
    int e = blockIdx.x * blockDim.x + threadIdx.x;
    if (e >= NE) return;
    int d = dst[e];
    int p = rowptr[d] + atomicAdd(&cnt[d], 1);
    eid[p] = src[e];
}

// ---------------- gather + prep: A[n][0:84] = bf16(h[n] + sum_{s in N(n)} h[s]),
// A[n][84:96] = 0. thread = (node, 4-feature chunk), 24 chunks/node ------------
__global__ void gather_prep(const float* __restrict__ h,
                            const int* __restrict__ rowptr,
                            const int* __restrict__ eid,
                            short* __restrict__ A) {
    int idx = blockIdx.x * blockDim.x + threadIdx.x;
    if (idx >= NN * 24) return;
    int n = idx / 24;
    int c = idx - n * 24;
    int lo_ = 0, hi_ = 0;
    if (c < 21) {
        const float4 self = *reinterpret_cast<const float4*>(h + (size_t)n * F0 + 4 * c);
        float a0 = self.x, a1 = self.y, a2 = self.z, a3 = self.w;
        int e0 = rowptr[n], e1 = rowptr[n + 1];
        for (int e = e0; e < e1; ++e) {
            int s = eid[e];
            const float4 v = *reinterpret_cast<const float4*>(h + (size_t)s * F0 + 4 * c);
            a0 += v.x; a1 += v.y; a2 += v.z; a3 += v.w;
        }
        lo_ = (unsigned short)f2bf(a0) | ((unsigned)(unsigned short)f2bf(a1) << 16);
        hi_ = (unsigned short)f2bf(a2) | ((unsigned)(unsigned short)f2bf(a3) << 16);
    }
    int2 o; o.x = lo_; o.y = hi_;
    *reinterpret_cast<int2*>(A + (size_t)n * 96 + 4 * c) = o;
}

// ---------------- pack W [K][N] fp32 -> fragment-ordered bf16 ----------------
__global__ void pack_w(const float* __restrict__ W, short* __restrict__ P,
                       int K, int N, int KB, int CT) {
    int idx = blockIdx.x * blockDim.x + threadIdx.x;
    if (idx >= CT * KB * 64) return;
    int lane = idx & 63;
    int t    = idx >> 6;
    int kb   = t % KB;
    int ct   = t / KB;
    int col  = ct * 16 + (lane & 15);
    int k0   = kb * 32 + ((lane >> 4) << 3);
    bf16x8 v;
#pragma unroll
    for (int j = 0; j < 8; ++j) {
        int k = k0 + j;
        float f = (k < K && col < N) ? W[(size_t)k * N + col] : 0.f;
        v[j] = f2bf(f);
    }
    *reinterpret_cast<bf16x8*>(P + (size_t)idx * 8) = v;
}

// ---------------- MFMA GEMM ----------------
template <bool RELU, bool OUTBF16>
__global__ void gemm16(const short* __restrict__ A, const short* __restrict__ Bp,
                       const float* __restrict__ bias, void* __restrict__ Cout,
                       int Kp, int N, int rowTiles, int ctPairs) {
    int gid  = blockIdx.x * blockDim.x + threadIdx.x;
    int w    = gid >> 6;
    if (w >= rowTiles * ctPairs) return;
    int lane = gid & 63;
    int rt   = w / ctPairs;
    int cp   = w - rt * ctPairs;
    int KB   = Kp >> 5;
    const short* Ap = A + (size_t)(rt * 16 + (lane & 15)) * Kp + ((lane >> 4) << 3);
    const short* B0 = Bp + (size_t)(cp * 2) * KB * 512 + lane * 8;
    const short* B1 = B0 + (size_t)KB * 512;
    f32x4 c0 = {0.f, 0.f, 0.f, 0.f}, c1 = {0.f, 0.f, 0.f, 0.f};
    for (int kb = 0; kb < KB; ++kb) {
        bf16x8 a  = *reinterpret_cast<const bf16x8*>(Ap + kb * 32);
        bf16x8 b0 = *reinterpret_cast<const bf16x8*>(B0 + kb * 512);
        bf16x8 b1 = *reinterpret_cast<const bf16x8*>(B1 + kb * 512);
        c0 = __builtin_amdgcn_mfma_f32_16x16x32_bf16(a, b0, c0, 0, 0, 0);
        c1 = __builtin_amdgcn_mfma_f32_16x16x32_bf16(a, b1, c1, 0, 0, 0);
    }
    int col0 = cp * 32 + (lane & 15);
    int col1 = col0 + 16;
    int row0 = rt * 16 + ((lane >> 4) << 2);
    float bias0 = (col0 < N) ? bias[col0] : 0.f;
    float bias1 = (col1 < N) ? bias[col1] : 0.f;
#pragma unroll
    for (int r = 0; r < 4; ++r) {
        int row = row0 + r;
        float v0 = c0[r] + bias0, v1 = c1[r] + bias1;
        if (RELU) { v0 = fmaxf(v0, 0.f); v1 = fmaxf(v1, 0.f); }
        if (OUTBF16) {
            short* C = (short*)Cout;
            if (col0 < N) C[(size_t)row * N + col0] = f2bf(v0);
            if (col1 < N) C[(size_t)row * N + col1] = f2bf(v1);
        } else {
            float* C = (float*)Cout;
            if (col0 < N) C[(size_t)row * N + col0] = v0;
            if (col1 < N) C[(size_t)row * N + col1] = v1;
        }
    }
}

// ---------------- graph starts (batch sorted) ----------------
__global__ void graph_starts(const int* __restrict__ batch, int* __restrict__ gstart) {
    int i = blockIdx.x * blockDim.x + threadIdx.x;
    if (i >= NN) return;
    int b = batch[i];
    if (i == 0) {
        for (int g = 0; g <= b; ++g) gstart[g] = 0;
    } else {
        int bp = batch[i - 1];
        for (int g = bp + 1; g <= b; ++g) gstart[g] = i;
    }
    if (i == NN - 1) {
        for (int g = b + 1; g <= NG; ++g) gstart[g] = NN;
    }
}

// ---------------- pool: bf16 [NG][1696]: [max(840) | sum(840) | 0 pad] --------
__global__ void pool_kernel(const float* __restrict__ h2,
                            const int* __restrict__ gstart,
                            short* __restrict__ A3) {
    int g = blockIdx.x;
    int t = threadIdx.x;  // 256
    int s = gstart[g], e = gstart[g + 1];
    float sm[4] = {0.f, 0.f, 0.f, 0.f};
    float mx[4] = {-INFINITY, -INFINITY, -INFINITY, -INFINITY};
    for (int n = s; n < e; ++n) {
        const float* row = h2 + (size_t)n * F2;
#pragma unroll
        for (int u = 0; u < 4; ++u) {
            int f = t + u * 256;
            if (f < F2) {
                float v = row[f];
                sm[u] += v;
                mx[u] = fmaxf(mx[u], v);
            }
        }
    }
    short* xr = A3 + (size_t)g * 1696;
#pragma unroll
    for (int u = 0; u < 4; ++u) {
        int f = t + u * 256;
        if (f < F2) {
            xr[f]      = f2bf(mx[u]);
            xr[F2 + f] = f2bf(sm[u]);
        }
    }
    if (t < 16) xr[1680 + t] = 0;
}

extern "C" void kernel_launch(void* const* d_in, const int* in_sizes, int n_in,
                              void* d_out, int out_size, void* d_ws, size_t ws_size,
                              hipStream_t stream) {
    const float* x    = (const float*)d_in[0];
    const int*   ei   = (const int*)d_in[1];
    const int*   batch= (const int*)d_in[2];
    const float* W1   = (const float*)d_in[3];
    const float* b1   = (const float*)d_in[4];
    const float* W2   = (const float*)d_in[5];
    const float* b2   = (const float*)d_in[6];
    const float* Wf1  = (const float*)d_in[7];
    const float* bf1  = (const float*)d_in[8];
    const float* Wf2  = (const float*)d_in[9];
    const float* bf2  = (const float*)d_in[10];

    const int* src = ei;
    const int* dst = ei + NE;

    float* xg_out = (float*)d_out;                    // [NG, FO]
    float* h2     = (float*)d_out + (size_t)NG * FO;  // [NN, F2]

    // workspace layout
    float* h1   = (float*)d_ws;                        // NN*84 f32
    short* A    = (short*)(h1 + (size_t)NN * F0);      // NN*96 bf16
    short* A3   = A + (size_t)NN * 96;                 // NG*1696 bf16
    short* fc1o = A3 + (size_t)NG * 1696;              // NG*1024 bf16
    short* W1p  = fc1o + (size_t)NG * FH;              // 6*3*512
    short* W2p  = W1p + 6 * 3 * 512;                   // 54*3*512
    short* Wf1p = W2p + 54 * 3 * 512;                  // 64*53*512
    short* Wf2p = Wf1p + (size_t)64 * 53 * 512;        // 24*32*512
    int*   deg  = (int*)(Wf2p + (size_t)24 * 32 * 512);// NN
    int*   cnt  = deg + NN;                            // NN
    int*   rowptr = cnt + NN;                          // NN+1
    int*   eid  = rowptr + NN + 1;                     // NE
    int*   gst  = eid + NE;                            // NG+1

    const int blk = 256;
    auto cdiv = [](long long a, long long b) { return (int)((a + b - 1) / b); };

    // ---- CSR build (deg & cnt zeroed in one memset; adjacent) ----
    hipMemsetAsync(deg, 0, 2 * (size_t)NN * sizeof(int), stream);
    edge_deg<<<cdiv(NE, blk), blk, 0, stream>>>(dst, deg);
    scan_deg<<<1, 1024, 0, stream>>>(deg, rowptr);
    edge_fill<<<cdiv(NE, blk), blk, 0, stream>>>(src, dst, rowptr, cnt, eid);

    // ---- pack weights ----
    pack_w<<<cdiv(6 * 3 * 64, blk), blk, 0, stream>>>(W1, W1p, F0, F0, 3, 6);
    pack_w<<<cdiv(54 * 3 * 64, blk), blk, 0, stream>>>(W2, W2p, F0, F2, 3, 54);
    pack_w<<<cdiv(64 * 53 * 64, blk), blk, 0, stream>>>(Wf1, Wf1p, 1680, FH, 53, 64);
    pack_w<<<cdiv(24 * 32 * 64, blk), blk, 0, stream>>>(Wf2, Wf2p, FH, FO, 32, 24);

    // ---- conv1: A = bf16(x + gather(x)); h1 = relu(A @ W1 + b1) ----
    gather_prep<<<cdiv((long long)NN * 24, blk), blk, 0, stream>>>(x, rowptr, eid, A);
    gemm16<true, false><<<cdiv(6250LL * 3 * 64, blk), blk, 0, stream>>>(
        A, W1p, b1, h1, 96, F0, 6250, 3);

    // ---- conv2: A = bf16(h1 + gather(h1)); h2 = relu(A @ W2 + b2) ----
    gather_prep<<<cdiv((long long)NN * 24, blk), blk, 0, stream>>>(h1, rowptr, eid, A);
    gemm16<true, false><<<cdiv(6250LL * 27 * 64, blk), blk, 0, stream>>>(
        A, W2p, b2, h2, 96, F2, 6250, 27);

    // ---- pooling ----
    graph_starts<<<cdiv(NN, blk), blk, 0, stream>>>(batch, gst);
    pool_kernel<<<NG, blk, 0, stream>>>(h2, gst, A3);

    // ---- fc head ----
    gemm16<true, true><<<cdiv(125LL * 32 * 64, blk), blk, 0, stream>>>(
        A3, Wf1p, bf1, fc1o, 1696, FH, 125, 32);
    gemm16<false, false><<<cdiv(125LL * 12 * 64, blk), blk, 0, stream>>>(
        fc1o, Wf2p, bf2, xg_out, 1024, FO, 125, 12);
}

// Round 4
// 418.642 us; speedup vs baseline: 9.0135x; 1.5850x over previous
//
#include <hip/hip_runtime.h>
#include <math.h>

#define NN 100000   // nodes
#define NE 400000   // edges
#define NG 2000     // graphs
#define F0 84       // num_features_xd
#define F2 840      // F0*10
#define FH 1024     // fc hidden
#define FO 384      // fc out

typedef __attribute__((ext_vector_type(8))) short bf16x8;
typedef __attribute__((ext_vector_type(4))) float f32x4;

__device__ inline short f2bf(float f) {
    union { float f; unsigned u; } v; v.f = f;
    unsigned r = (v.u + 0x7FFFu + ((v.u >> 16) & 1u)) >> 16;
    return (short)r;
}
__device__ inline float b2f(short s) {
    union { unsigned u; float f; } v;
    v.u = ((unsigned)(unsigned short)s) << 16;
    return v.f;
}

// ---------------- CSR build ----------------
__global__ void edge_deg(const int* __restrict__ dst, int* __restrict__ deg) {
    int e = blockIdx.x * blockDim.x + threadIdx.x;
    if (e < NE) atomicAdd(&deg[dst[e]], 1);
}

// phase 1: per-block inclusive scan (1024 elems/block); rowptr[i] = local exclusive
__global__ void scan_ph1(const int* __restrict__ deg, int* __restrict__ rowptr,
                         int* __restrict__ bsum) {
    __shared__ int s[1024];
    int t = threadIdx.x;
    int i = blockIdx.x * 1024 + t;
    int v = (i < NN) ? deg[i] : 0;
    s[t] = v;
    __syncthreads();
    for (int d = 1; d < 1024; d <<= 1) {
        int u = (t >= d) ? s[t - d] : 0;
        __syncthreads();
        s[t] += u;
        __syncthreads();
    }
    if (i < NN) rowptr[i] = s[t] - v;
    if (t == 1023) bsum[blockIdx.x] = s[t];
}

// phase 2: exclusive scan of 98 block sums (1 block, 128 threads)
__global__ void scan_ph2(int* __restrict__ bsum, int nb) {
    __shared__ int s[128];
    int t = threadIdx.x;
    int v = (t < nb) ? bsum[t] : 0;
    s[t] = v;
    __syncthreads();
    for (int d = 1; d < 128; d <<= 1) {
        int u = (t >= d) ? s[t - d] : 0;
        __syncthreads();
        s[t] += u;
        __syncthreads();
    }
    if (t < nb) bsum[t] = s[t] - v;
}

// phase 3: add block offsets; set rowptr[NN] = NE
__global__ void scan_ph3(int* __restrict__ rowptr, const int* __restrict__ bsum) {
    int t = threadIdx.x;
    int i = blockIdx.x * 1024 + t;
    if (i < NN) rowptr[i] += bsum[blockIdx.x];
    if (i == 0) rowptr[NN] = NE;
}

__global__ void edge_fill(const int* __restrict__ src, const int* __restrict__ dst,
                          const int* __restrict__ rowptr, int* __restrict__ cnt,
                          int* __restrict__ eid) {
    int e = blockIdx.x * blockDim.x + threadIdx.x;
    if (e >= NE) return;
    int d = dst[e];
    int p = rowptr[d] + atomicAdd(&cnt[d], 1);
    eid[p] = src[e];
}

// ---------------- cast x fp32 -> bf16 [NN][96] (zero pad) ----------------
__global__ void cast_x(const float* __restrict__ x, short* __restrict__ Xb) {
    int idx = blockIdx.x * blockDim.x + threadIdx.x;
    if (idx >= NN * 12) return;
    int n = idx / 12;
    int c = idx - n * 12;
    int k0 = c * 8;
    bf16x8 v;
#pragma unroll
    for (int j = 0; j < 8; ++j) {
        int k = k0 + j;
        v[j] = (k < F0) ? f2bf(x[(size_t)n * F0 + k]) : (short)0;
    }
    *reinterpret_cast<bf16x8*>(Xb + (size_t)n * 96 + k0) = v;
}

// ---------------- gather (bf16 in, bf16 out): A[n] = H[n] + sum_nbr H[s] ------
__global__ void gather_bf16(const short* __restrict__ H,
                            const int* __restrict__ rowptr,
                            const int* __restrict__ eid,
                            short* __restrict__ A) {
    int idx = blockIdx.x * blockDim.x + threadIdx.x;
    if (idx >= NN * 12) return;
    int n = idx / 12;
    int c = idx - n * 12;
    int off = c * 8;
    bf16x8 sv = *reinterpret_cast<const bf16x8*>(H + (size_t)n * 96 + off);
    float acc[8];
#pragma unroll
    for (int j = 0; j < 8; ++j) acc[j] = b2f(sv[j]);
    int e0 = rowptr[n], e1 = rowptr[n + 1];
    for (int e = e0; e < e1; ++e) {
        int s = eid[e];
        bf16x8 v = *reinterpret_cast<const bf16x8*>(H + (size_t)s * 96 + off);
#pragma unroll
        for (int j = 0; j < 8; ++j) acc[j] += b2f(v[j]);
    }
    bf16x8 o;
#pragma unroll
    for (int j = 0; j < 8; ++j) o[j] = f2bf(acc[j]);
    *reinterpret_cast<bf16x8*>(A + (size_t)n * 96 + off) = o;
}

// ---------------- pack all weights -> fragment-ordered bf16 ----------------
__device__ inline void pack_one(const float* __restrict__ W, short* __restrict__ P,
                                int K, int N, int KB, int CT, int idx) {
    int lane = idx & 63;
    int t    = idx >> 6;
    int kb   = t % KB;
    int ct   = t / KB;
    int col  = ct * 16 + (lane & 15);
    int k0   = kb * 32 + ((lane >> 4) << 3);
    bf16x8 v;
#pragma unroll
    for (int j = 0; j < 8; ++j) {
        int k = k0 + j;
        float f = (k < K && col < N) ? W[(size_t)k * N + col] : 0.f;
        v[j] = f2bf(f);
    }
    *reinterpret_cast<bf16x8*>(P + (size_t)idx * 8) = v;
}

#define S1 (6*3*64)
#define S2 (54*3*64)
#define S3 (64*53*64)
#define S4 (24*32*64)
__global__ void pack_all(const float* __restrict__ W1, short* __restrict__ P1,
                         const float* __restrict__ W2, short* __restrict__ P2,
                         const float* __restrict__ Wf1, short* __restrict__ P3,
                         const float* __restrict__ Wf2, short* __restrict__ P4) {
    int idx = blockIdx.x * blockDim.x + threadIdx.x;
    if (idx < S1) { pack_one(W1, P1, F0, F0, 3, 6, idx); return; }
    idx -= S1;
    if (idx < S2) { pack_one(W2, P2, F0, F2, 3, 54, idx); return; }
    idx -= S2;
    if (idx < S3) { pack_one(Wf1, P3, 1680, FH, 53, 64, idx); return; }
    idx -= S3;
    if (idx < S4) { pack_one(Wf2, P4, FH, FO, 32, 24, idx); return; }
}

// ---------------- MFMA GEMM, CTW col-tiles per wave ----------------
template <int CTW, bool RELU, bool OUTBF16>
__global__ void gemmN(const short* __restrict__ A, const short* __restrict__ Bp,
                      const float* __restrict__ bias, void* __restrict__ Cout,
                      int Kp, int Nbias, int ldc, int ncols,
                      int rowTiles, int ctGroups) {
    int gid = blockIdx.x * blockDim.x + threadIdx.x;
    int w   = gid >> 6;
    if (w >= rowTiles * ctGroups) return;
    int lane = gid & 63;
    int rt = w / ctGroups;
    int cg = w - rt * ctGroups;
    int KB = Kp >> 5;
    const short* Ap = A + (size_t)(rt * 16 + (lane & 15)) * Kp + ((lane >> 4) << 3);
    const short* Bbase = Bp + (size_t)(cg * CTW) * KB * 512 + lane * 8;
    f32x4 acc[CTW];
#pragma unroll
    for (int u = 0; u < CTW; ++u) acc[u] = (f32x4){0.f, 0.f, 0.f, 0.f};
    for (int kb = 0; kb < KB; ++kb) {
        bf16x8 a = *reinterpret_cast<const bf16x8*>(Ap + kb * 32);
#pragma unroll
        for (int u = 0; u < CTW; ++u) {
            bf16x8 b = *reinterpret_cast<const bf16x8*>(Bbase + ((size_t)u * KB + kb) * 512);
            acc[u] = __builtin_amdgcn_mfma_f32_16x16x32_bf16(a, b, acc[u], 0, 0, 0);
        }
    }
    int row0 = rt * 16 + ((lane >> 4) << 2);
#pragma unroll
    for (int u = 0; u < CTW; ++u) {
        int col = (cg * CTW + u) * 16 + (lane & 15);
        float bi = (col < Nbias) ? bias[col] : 0.f;
        if (col < ncols) {
#pragma unroll
            for (int r = 0; r < 4; ++r) {
                int row = row0 + r;
                float v = acc[u][r] + bi;
                if (RELU) v = fmaxf(v, 0.f);
                if (OUTBF16) ((short*)Cout)[(size_t)row * ldc + col] = f2bf(v);
                else         ((float*)Cout)[(size_t)row * ldc + col] = v;
            }
        }
    }
}

// ---------------- graph starts (batch sorted) ----------------
__global__ void graph_starts(const int* __restrict__ batch, int* __restrict__ gstart) {
    int i = blockIdx.x * blockDim.x + threadIdx.x;
    if (i >= NN) return;
    int b = batch[i];
    if (i == 0) {
        for (int g = 0; g <= b; ++g) gstart[g] = 0;
    } else {
        int bp = batch[i - 1];
        for (int g = bp + 1; g <= b; ++g) gstart[g] = i;
    }
    if (i == NN - 1) {
        for (int g = b + 1; g <= NG; ++g) gstart[g] = NN;
    }
}

// ---------------- pool: bf16 [NG][1696]: [max(840) | sum(840) | 0 pad] --------
__global__ void pool_kernel(const float* __restrict__ h2,
                            const int* __restrict__ gstart,
                            short* __restrict__ A3) {
    int g = blockIdx.x;
    int t = threadIdx.x;  // 256
    int s = gstart[g], e = gstart[g + 1];
    float sm[4] = {0.f, 0.f, 0.f, 0.f};
    float mx[4] = {-INFINITY, -INFINITY, -INFINITY, -INFINITY};
    int n = s;
    for (; n + 1 < e; n += 2) {
        const float* r0 = h2 + (size_t)n * F2;
        const float* r1 = r0 + F2;
#pragma unroll
        for (int u = 0; u < 4; ++u) {
            int f = t + u * 256;
            if (f < F2) {
                float v0 = r0[f], v1 = r1[f];
                sm[u] += v0 + v1;
                mx[u] = fmaxf(mx[u], fmaxf(v0, v1));
            }
        }
    }
    if (n < e) {
        const float* r0 = h2 + (size_t)n * F2;
#pragma unroll
        for (int u = 0; u < 4; ++u) {
            int f = t + u * 256;
            if (f < F2) {
                float v0 = r0[f];
                sm[u] += v0;
                mx[u] = fmaxf(mx[u], v0);
            }
        }
    }
    short* xr = A3 + (size_t)g * 1696;
#pragma unroll
    for (int u = 0; u < 4; ++u) {
        int f = t + u * 256;
        if (f < F2) {
            xr[f]      = f2bf(mx[u]);
            xr[F2 + f] = f2bf(sm[u]);
        }
    }
    if (t < 16) xr[1680 + t] = 0;
}

extern "C" void kernel_launch(void* const* d_in, const int* in_sizes, int n_in,
                              void* d_out, int out_size, void* d_ws, size_t ws_size,
                              hipStream_t stream) {
    const float* x    = (const float*)d_in[0];
    const int*   ei   = (const int*)d_in[1];
    const int*   batch= (const int*)d_in[2];
    const float* W1   = (const float*)d_in[3];
    const float* b1   = (const float*)d_in[4];
    const float* W2   = (const float*)d_in[5];
    const float* b2   = (const float*)d_in[6];
    const float* Wf1  = (const float*)d_in[7];
    const float* bf1  = (const float*)d_in[8];
    const float* Wf2  = (const float*)d_in[9];
    const float* bf2  = (const float*)d_in[10];

    const int* src = ei;
    const int* dst = ei + NE;

    float* xg_out = (float*)d_out;                    // [NG, FO]
    float* h2     = (float*)d_out + (size_t)NG * FO;  // [NN, F2] fp32

    // workspace layout (bf16 buffers are 16B-aligned by construction)
    short* Xb   = (short*)d_ws;                        // NN*96
    short* A    = Xb + (size_t)NN * 96;                // NN*96
    short* h1   = A  + (size_t)NN * 96;                // NN*96
    short* A3   = h1 + (size_t)NN * 96;                // NG*1696
    short* fc1o = A3 + (size_t)NG * 1696;              // NG*1024
    short* W1p  = fc1o + (size_t)NG * FH;              // S1*8
    short* W2p  = W1p + (size_t)S1 * 8;                // S2*8
    short* Wf1p = W2p + (size_t)S2 * 8;                // S3*8
    short* Wf2p = Wf1p + (size_t)S3 * 8;               // S4*8
    int*   deg  = (int*)(Wf2p + (size_t)S4 * 8);       // NN
    int*   cnt  = deg + NN;                            // NN
    int*   rowptr = cnt + NN;                          // NN+1
    int*   bsum = rowptr + NN + 1;                     // 128
    int*   eid  = bsum + 128;                          // NE
    int*   gst  = eid + NE;                            // NG+1

    const int blk = 256;
    auto cdiv = [](long long a, long long b) { return (int)((a + b - 1) / b); };
    const int nb1024 = cdiv(NN, 1024);  // 98

    // ---- CSR build ----
    hipMemsetAsync(deg, 0, 2 * (size_t)NN * sizeof(int), stream);
    edge_deg<<<cdiv(NE, blk), blk, 0, stream>>>(dst, deg);
    scan_ph1<<<nb1024, 1024, 0, stream>>>(deg, rowptr, bsum);
    scan_ph2<<<1, 128, 0, stream>>>(bsum, nb1024);
    scan_ph3<<<nb1024, 1024, 0, stream>>>(rowptr, bsum);
    edge_fill<<<cdiv(NE, blk), blk, 0, stream>>>(src, dst, rowptr, cnt, eid);

    // ---- pack weights (one launch) ----
    pack_all<<<cdiv(S1 + S2 + S3 + S4, blk), blk, 0, stream>>>(
        W1, W1p, W2, W2p, Wf1, Wf1p, Wf2, Wf2p);

    // ---- conv1: Xb = bf16(x); A = Xb + gather(Xb); h1 = bf16(relu(A@W1+b1)) ----
    cast_x<<<cdiv((long long)NN * 12, blk), blk, 0, stream>>>(x, Xb);
    gather_bf16<<<cdiv((long long)NN * 12, blk), blk, 0, stream>>>(Xb, rowptr, eid, A);
    gemmN<6, true, true><<<cdiv(6250LL * 1 * 64, blk), blk, 0, stream>>>(
        A, W1p, b1, h1, 96, F0, 96, 96, 6250, 1);

    // ---- conv2: A = h1 + gather(h1); h2 = relu(A@W2+b2) fp32 ----
    gather_bf16<<<cdiv((long long)NN * 12, blk), blk, 0, stream>>>(h1, rowptr, eid, A);
    gemmN<6, true, false><<<cdiv(6250LL * 9 * 64, blk), blk, 0, stream>>>(
        A, W2p, b2, h2, 96, F2, F2, F2, 6250, 9);

    // ---- pooling ----
    graph_starts<<<cdiv(NN, blk), blk, 0, stream>>>(batch, gst);
    pool_kernel<<<NG, blk, 0, stream>>>(h2, gst, A3);

    // ---- fc head ----
    gemmN<2, true, true><<<cdiv(125LL * 32 * 64, blk), blk, 0, stream>>>(
        A3, Wf1p, bf1, fc1o, 1696, FH, FH, FH, 125, 32);
    gemmN<2, false, false><<<cdiv(125LL * 12 * 64, blk), blk, 0, stream>>>(
        fc1o, Wf2p, bf2, xg_out, 1024, FO, FO, FO, 125, 12);
}

// Round 5
// 408.596 us; speedup vs baseline: 9.2351x; 1.0246x over previous
//
#include <hip/hip_runtime.h>
#include <math.h>

#define NN 100000   // nodes
#define NE 400000   // edges
#define NG 2000     // graphs
#define F0 84       // num_features_xd
#define F2 840      // F0*10
#define FH 1024     // fc hidden
#define FO 384      // fc out

typedef __attribute__((ext_vector_type(8))) short bf16x8;
typedef __attribute__((ext_vector_type(4))) float f32x4;

__device__ inline short f2bf(float f) {
    union { float f; unsigned u; } v; v.f = f;
    unsigned r = (v.u + 0x7FFFu + ((v.u >> 16) & 1u)) >> 16;
    return (short)r;
}
__device__ inline float b2f(short s) {
    union { unsigned u; float f; } v;
    v.u = ((unsigned)(unsigned short)s) << 16;
    return v.f;
}

// ---------------- CSR build ----------------
__global__ void edge_deg(const int* __restrict__ dst, int* __restrict__ deg) {
    int e = blockIdx.x * blockDim.x + threadIdx.x;
    if (e < NE) atomicAdd(&deg[dst[e]], 1);
}

__global__ void scan_ph1(const int* __restrict__ deg, int* __restrict__ rowptr,
                         int* __restrict__ bsum) {
    __shared__ int s[1024];
    int t = threadIdx.x;
    int i = blockIdx.x * 1024 + t;
    int v = (i < NN) ? deg[i] : 0;
    s[t] = v;
    __syncthreads();
    for (int d = 1; d < 1024; d <<= 1) {
        int u = (t >= d) ? s[t - d] : 0;
        __syncthreads();
        s[t] += u;
        __syncthreads();
    }
    if (i < NN) rowptr[i] = s[t] - v;
    if (t == 1023) bsum[blockIdx.x] = s[t];
}

__global__ void scan_ph2(int* __restrict__ bsum, int nb) {
    __shared__ int s[128];
    int t = threadIdx.x;
    int v = (t < nb) ? bsum[t] : 0;
    s[t] = v;
    __syncthreads();
    for (int d = 1; d < 128; d <<= 1) {
        int u = (t >= d) ? s[t - d] : 0;
        __syncthreads();
        s[t] += u;
        __syncthreads();
    }
    if (t < nb) bsum[t] = s[t] - v;
}

__global__ void scan_ph3(int* __restrict__ rowptr, const int* __restrict__ bsum) {
    int t = threadIdx.x;
    int i = blockIdx.x * 1024 + t;
    if (i < NN) rowptr[i] += bsum[blockIdx.x];
    if (i == 0) rowptr[NN] = NE;
}

__global__ void edge_fill(const int* __restrict__ src, const int* __restrict__ dst,
                          const int* __restrict__ rowptr, int* __restrict__ cnt,
                          int* __restrict__ eid) {
    int e = blockIdx.x * blockDim.x + threadIdx.x;
    if (e >= NE) return;
    int d = dst[e];
    int p = rowptr[d] + atomicAdd(&cnt[d], 1);
    eid[p] = src[e];
}

// ---------------- cast x fp32 -> bf16 [NN][96] (zero pad) ----------------
__global__ void cast_x(const float* __restrict__ x, short* __restrict__ Xb) {
    int idx = blockIdx.x * blockDim.x + threadIdx.x;
    if (idx >= NN * 12) return;
    int n = idx / 12;
    int c = idx - n * 12;
    int k0 = c * 8;
    bf16x8 v;
#pragma unroll
    for (int j = 0; j < 8; ++j) {
        int k = k0 + j;
        v[j] = (k < F0) ? f2bf(x[(size_t)n * F0 + k]) : (short)0;
    }
    *reinterpret_cast<bf16x8*>(Xb + (size_t)n * 96 + k0) = v;
}

// ---------------- pack weights -> fragment-ordered bf16 ----------------
__device__ inline void pack_one(const float* __restrict__ W, short* __restrict__ P,
                                int K, int N, int KB, int CT, int idx) {
    int lane = idx & 63;
    int t    = idx >> 6;
    int kb   = t % KB;
    int ct   = t / KB;
    int col  = ct * 16 + (lane & 15);
    int k0   = kb * 32 + ((lane >> 4) << 3);
    bf16x8 v;
#pragma unroll
    for (int j = 0; j < 8; ++j) {
        int k = k0 + j;
        float f = (k < K && col < N) ? W[(size_t)k * N + col] : 0.f;
        v[j] = f2bf(f);
    }
    *reinterpret_cast<bf16x8*>(P + (size_t)idx * 8) = v;
}

#define S1 (6*3*64)
#define S2 (56*3*64)
#define S3 (64*53*64)
#define S4 (24*32*64)
__global__ void pack_all(const float* __restrict__ W1, short* __restrict__ P1,
                         const float* __restrict__ W2, short* __restrict__ P2,
                         const float* __restrict__ Wf1, short* __restrict__ P3,
                         const float* __restrict__ Wf2, short* __restrict__ P4) {
    int idx = blockIdx.x * blockDim.x + threadIdx.x;
    if (idx < S1) { pack_one(W1, P1, F0, F0, 3, 6, idx); return; }
    idx -= S1;
    if (idx < S2) { pack_one(W2, P2, F0, F2, 3, 56, idx); return; }
    idx -= S2;
    if (idx < S3) { pack_one(Wf1, P3, 1680, FH, 53, 64, idx); return; }
    idx -= S3;
    if (idx < S4) { pack_one(Wf2, P4, FH, FO, 32, 24, idx); return; }
}

// ---------------- fused gather + GIN dense (relu) ----------------
// Block = NWAVES waves, one 16-row tile. Phase 1: gather neighbor sums for the
// 16 rows into LDS in MFMA fragment order [kb][lane][8] (conflict-free b128
// reads in phase 2). Phase 2: each wave MFMAs CTW col-tiles. K fixed = 96.
template <int CTW, int NWAVES, bool OUTBF16>
__global__ void conv_fused(const short* __restrict__ H,
                           const int* __restrict__ rowptr,
                           const int* __restrict__ eid,
                           const short* __restrict__ Bp,
                           const float* __restrict__ bias,
                           void* __restrict__ Cout,
                           int Nbias, int ldc, int ncols) {
    __shared__ short Alds[3 * 512];
    int rt = blockIdx.x;
    int t  = threadIdx.x;

    // ---- gather phase: 192 items = (row r, 8-elem chunk c) ----
    for (int item = t; item < 192; item += NWAVES * 64) {
        int r = item / 12;
        int c = item - r * 12;
        int n = rt * 16 + r;
        int off = c * 8;
        bf16x8 sv = *reinterpret_cast<const bf16x8*>(H + (size_t)n * 96 + off);
        float acc[8];
#pragma unroll
        for (int j = 0; j < 8; ++j) acc[j] = b2f(sv[j]);
        int e0 = rowptr[n], e1 = rowptr[n + 1];
        for (int e = e0; e < e1; ++e) {
            int s = eid[e];
            bf16x8 v = *reinterpret_cast<const bf16x8*>(H + (size_t)s * 96 + off);
#pragma unroll
            for (int j = 0; j < 8; ++j) acc[j] += b2f(v[j]);
        }
        bf16x8 o;
#pragma unroll
        for (int j = 0; j < 8; ++j) o[j] = f2bf(acc[j]);
        // fragment layout: kb = c/4, lane = (c%4)*16 + r
        int kb = c >> 2, q = c & 3;
        *reinterpret_cast<bf16x8*>(&Alds[(kb * 512) + (q * 16 + r) * 8]) = o;
    }
    __syncthreads();

    // ---- GEMM phase ----
    int wave = t >> 6;
    int lane = t & 63;
    f32x4 acc[CTW];
#pragma unroll
    for (int u = 0; u < CTW; ++u) acc[u] = (f32x4){0.f, 0.f, 0.f, 0.f};
    const short* Bbase = Bp + (size_t)(wave * CTW) * 3 * 512 + lane * 8;
#pragma unroll
    for (int kb = 0; kb < 3; ++kb) {
        bf16x8 a = *reinterpret_cast<const bf16x8*>(&Alds[kb * 512 + lane * 8]);
#pragma unroll
        for (int u = 0; u < CTW; ++u) {
            bf16x8 b = *reinterpret_cast<const bf16x8*>(Bbase + ((size_t)u * 3 + kb) * 512);
            acc[u] = __builtin_amdgcn_mfma_f32_16x16x32_bf16(a, b, acc[u], 0, 0, 0);
        }
    }
    int row0 = rt * 16 + ((lane >> 4) << 2);
#pragma unroll
    for (int u = 0; u < CTW; ++u) {
        int col = (wave * CTW + u) * 16 + (lane & 15);
        float bi = (col < Nbias) ? bias[col] : 0.f;
        if (col < ncols) {
#pragma unroll
            for (int r = 0; r < 4; ++r) {
                float v = fmaxf(acc[u][r] + bi, 0.f);
                if (OUTBF16) ((short*)Cout)[(size_t)(row0 + r) * ldc + col] = f2bf(v);
                else         ((float*)Cout)[(size_t)(row0 + r) * ldc + col] = v;
            }
        }
    }
}

// ---------------- plain MFMA GEMM (fc head) ----------------
template <int CTW, bool RELU, bool OUTBF16>
__global__ void gemmN(const short* __restrict__ A, const short* __restrict__ Bp,
                      const float* __restrict__ bias, void* __restrict__ Cout,
                      int Kp, int Nbias, int ldc, int ncols,
                      int rowTiles, int ctGroups) {
    int gid = blockIdx.x * blockDim.x + threadIdx.x;
    int w   = gid >> 6;
    if (w >= rowTiles * ctGroups) return;
    int lane = gid & 63;
    int rt = w / ctGroups;
    int cg = w - rt * ctGroups;
    int KB = Kp >> 5;
    const short* Ap = A + (size_t)(rt * 16 + (lane & 15)) * Kp + ((lane >> 4) << 3);
    const short* Bbase = Bp + (size_t)(cg * CTW) * KB * 512 + lane * 8;
    f32x4 acc[CTW];
#pragma unroll
    for (int u = 0; u < CTW; ++u) acc[u] = (f32x4){0.f, 0.f, 0.f, 0.f};
    for (int kb = 0; kb < KB; ++kb) {
        bf16x8 a = *reinterpret_cast<const bf16x8*>(Ap + kb * 32);
#pragma unroll
        for (int u = 0; u < CTW; ++u) {
            bf16x8 b = *reinterpret_cast<const bf16x8*>(Bbase + ((size_t)u * KB + kb) * 512);
            acc[u] = __builtin_amdgcn_mfma_f32_16x16x32_bf16(a, b, acc[u], 0, 0, 0);
        }
    }
    int row0 = rt * 16 + ((lane >> 4) << 2);
#pragma unroll
    for (int u = 0; u < CTW; ++u) {
        int col = (cg * CTW + u) * 16 + (lane & 15);
        float bi = (col < Nbias) ? bias[col] : 0.f;
        if (col < ncols) {
#pragma unroll
            for (int r = 0; r < 4; ++r) {
                int row = row0 + r;
                float v = acc[u][r] + bi;
                if (RELU) v = fmaxf(v, 0.f);
                if (OUTBF16) ((short*)Cout)[(size_t)row * ldc + col] = f2bf(v);
                else         ((float*)Cout)[(size_t)row * ldc + col] = v;
            }
        }
    }
}

// ---------------- pool: block g; segment via binary search on batch ----------
__global__ void pool_kernel(const float* __restrict__ h2,
                            const int* __restrict__ batch,
                            short* __restrict__ A3) {
    int g = blockIdx.x;
    int t = threadIdx.x;  // 256
    __shared__ int se[2];
    if (t < 2) {
        int target = g + t;
        int lo = 0, hi = NN;
        while (lo < hi) {
            int mid = (lo + hi) >> 1;
            if (batch[mid] < target) lo = mid + 1; else hi = mid;
        }
        se[t] = lo;
    }
    __syncthreads();
    int s = se[0], e = se[1];
    if (t < 210) {
        int c4 = t * 4;
        float sm0 = 0.f, sm1 = 0.f, sm2 = 0.f, sm3 = 0.f;
        float mx0 = -INFINITY, mx1 = -INFINITY, mx2 = -INFINITY, mx3 = -INFINITY;
        for (int n = s; n < e; ++n) {
            float4 v = *reinterpret_cast<const float4*>(h2 + (size_t)n * F2 + c4);
            sm0 += v.x; sm1 += v.y; sm2 += v.z; sm3 += v.w;
            mx0 = fmaxf(mx0, v.x); mx1 = fmaxf(mx1, v.y);
            mx2 = fmaxf(mx2, v.z); mx3 = fmaxf(mx3, v.w);
        }
        short* xr = A3 + (size_t)g * 1696;
        short4 mo, so;
        mo.x = f2bf(mx0); mo.y = f2bf(mx1); mo.z = f2bf(mx2); mo.w = f2bf(mx3);
        so.x = f2bf(sm0); so.y = f2bf(sm1); so.z = f2bf(sm2); so.w = f2bf(sm3);
        *reinterpret_cast<short4*>(xr + c4)      = mo;
        *reinterpret_cast<short4*>(xr + F2 + c4) = so;
    }
    if (t >= 210 && t < 214) {
        // zero pad cols 1680..1695
        short4 z = {0, 0, 0, 0};
        *reinterpret_cast<short4*>(A3 + (size_t)g * 1696 + 1680 + (t - 210) * 4) = z;
    }
}

extern "C" void kernel_launch(void* const* d_in, const int* in_sizes, int n_in,
                              void* d_out, int out_size, void* d_ws, size_t ws_size,
                              hipStream_t stream) {
    const float* x    = (const float*)d_in[0];
    const int*   ei   = (const int*)d_in[1];
    const int*   batch= (const int*)d_in[2];
    const float* W1   = (const float*)d_in[3];
    const float* b1   = (const float*)d_in[4];
    const float* W2   = (const float*)d_in[5];
    const float* b2   = (const float*)d_in[6];
    const float* Wf1  = (const float*)d_in[7];
    const float* bf1  = (const float*)d_in[8];
    const float* Wf2  = (const float*)d_in[9];
    const float* bf2  = (const float*)d_in[10];

    const int* src = ei;
    const int* dst = ei + NE;

    float* xg_out = (float*)d_out;                    // [NG, FO]
    float* h2     = (float*)d_out + (size_t)NG * FO;  // [NN, F2] fp32

    // workspace layout
    short* Xb   = (short*)d_ws;                        // NN*96
    short* h1   = Xb + (size_t)NN * 96;                // NN*96
    short* A3   = h1 + (size_t)NN * 96;                // NG*1696
    short* fc1o = A3 + (size_t)NG * 1696;              // NG*1024
    short* W1p  = fc1o + (size_t)NG * FH;              // S1*8
    short* W2p  = W1p + (size_t)S1 * 8;                // S2*8
    short* Wf1p = W2p + (size_t)S2 * 8;                // S3*8
    short* Wf2p = Wf1p + (size_t)S3 * 8;               // S4*8
    int*   deg  = (int*)(Wf2p + (size_t)S4 * 8);       // NN
    int*   cnt  = deg + NN;                            // NN
    int*   rowptr = cnt + NN;                          // NN+1
    int*   bsum = rowptr + NN + 1;                     // 128
    int*   eid  = bsum + 128;                          // NE

    const int blk = 256;
    auto cdiv = [](long long a, long long b) { return (int)((a + b - 1) / b); };
    const int nb1024 = cdiv(NN, 1024);  // 98

    // ---- CSR build ----
    hipMemsetAsync(deg, 0, 2 * (size_t)NN * sizeof(int), stream);
    edge_deg<<<cdiv(NE, blk), blk, 0, stream>>>(dst, deg);
    scan_ph1<<<nb1024, 1024, 0, stream>>>(deg, rowptr, bsum);
    scan_ph2<<<1, 128, 0, stream>>>(bsum, nb1024);
    scan_ph3<<<nb1024, 1024, 0, stream>>>(rowptr, bsum);
    edge_fill<<<cdiv(NE, blk), blk, 0, stream>>>(src, dst, rowptr, cnt, eid);

    // ---- weights + x cast ----
    pack_all<<<cdiv(S1 + S2 + S3 + S4, blk), blk, 0, stream>>>(
        W1, W1p, W2, W2p, Wf1, Wf1p, Wf2, Wf2p);
    cast_x<<<cdiv((long long)NN * 12, blk), blk, 0, stream>>>(x, Xb);

    // ---- conv1 (fused gather+gemm): h1 = bf16(relu((Xb+gather)@W1+b1)) ----
    conv_fused<6, 1, true><<<6250, 64, 0, stream>>>(
        Xb, rowptr, eid, W1p, b1, h1, F0, 96, 96);

    // ---- conv2 (fused): h2 = relu((h1+gather)@W2+b2) fp32 ----
    conv_fused<14, 4, false><<<6250, 256, 0, stream>>>(
        h1, rowptr, eid, W2p, b2, h2, F2, F2, F2);

    // ---- pooling (binary-search segments) ----
    pool_kernel<<<NG, blk, 0, stream>>>(h2, batch, A3);

    // ---- fc head ----
    gemmN<2, true, true><<<cdiv(125LL * 32 * 64, blk), blk, 0, stream>>>(
        A3, Wf1p, bf1, fc1o, 1696, FH, FH, FH, 125, 32);
    gemmN<2, false, false><<<cdiv(125LL * 12 * 64, blk), blk, 0, stream>>>(
        fc1o, Wf2p, bf2, xg_out, 1024, FO, FO, FO, 125, 12);
}